// Round 2
// baseline (55.193 us; speedup 1.0000x reference)
//
#include <hip/hip_runtime.h>

#define MARGIN 0.3f
#define ANCHOR 0.5f
#define EPS    1e-8f
#define BJ     256

typedef unsigned long long ull;

// ---------------- kernel 1: s_q, quality, and accumulator zero-init ----------------
// One wave (64 lanes) per row of d_embs; float4 loads; butterfly reduce.
__global__ __launch_bounds__(256) void sq_kernel(
        const float* __restrict__ q, const float* __restrict__ d,
        const float* __restrict__ rates,
        float* __restrict__ sq, float* __restrict__ qual,
        double* __restrict__ total, ull* __restrict__ cnt, unsigned* __restrict__ done,
        int N, int D) {
    if (blockIdx.x == 0 && threadIdx.x == 0) {
        *total = 0.0;
        *cnt   = 0ull;
        *done  = 0u;
    }
    int wave = (blockIdx.x * blockDim.x + threadIdx.x) >> 6;
    int lane = threadIdx.x & 63;
    if (wave >= N) return;
    const float* row = d + (size_t)wave * (size_t)D;

    float dot = 0.f, dn = 0.f, qn = 0.f;
    for (int it = lane * 4; it < D; it += 256) {
        float4 dv = *(const float4*)(row + it);
        float4 qv = *(const float4*)(q + it);
        dot += dv.x * qv.x + dv.y * qv.y + dv.z * qv.z + dv.w * qv.w;
        dn  += dv.x * dv.x + dv.y * dv.y + dv.z * dv.z + dv.w * dv.w;
        qn  += qv.x * qv.x + qv.y * qv.y + qv.z * qv.z + qv.w * qv.w;
    }
    #pragma unroll
    for (int off = 32; off >= 1; off >>= 1) {
        dot += __shfl_xor(dot, off);
        dn  += __shfl_xor(dn,  off);
        qn  += __shfl_xor(qn,  off);
    }
    if (lane == 0) {
        float den = fmaxf(sqrtf(dn) * sqrtf(qn), EPS);
        sq[wave]   = dot / den;
        qual[wave] = fabsf(rates[wave] - ANCHOR);
    }
}

// ---------------- kernel 2: N^2 pair reduction + last-block finalize ----------------
// grid = (N/256, N/BJ). Thread owns i; j-tile read with wave-uniform float4
// loads (scalar-cache path, no LDS, no syncthreads in the hot loop).
__global__ __launch_bounds__(256) void pair_kernel(
        const float* __restrict__ sq, const float* __restrict__ qual,
        int N, double* __restrict__ total, ull* __restrict__ cnt,
        unsigned* __restrict__ done, float* __restrict__ out, unsigned nblocks) {
    int tid = threadIdx.x;
    int i   = blockIdx.x * blockDim.x + tid;
    int j0  = blockIdx.y * BJ;

    float my_sq = (i < N) ? sq[i]   : 0.f;
    float my_q  = (i < N) ? qual[i] : -1.f;   // quality >= 0 -> masks everything off
    float a     = MARGIN - my_sq;

    const float4* sq4 = (const float4*)(sq   + j0);
    const float4* qu4 = (const float4*)(qual + j0);

    float sum = 0.f;
    unsigned c = 0;
    #pragma unroll 4
    for (int j = 0; j < BJ / 4; ++j) {
        float4 sv = sq4[j];
        float4 qv = qu4[j];
        bool m0 = my_q > qv.x;  float v0 = fmaxf(a + sv.x, 0.f);
        bool m1 = my_q > qv.y;  float v1 = fmaxf(a + sv.y, 0.f);
        bool m2 = my_q > qv.z;  float v2 = fmaxf(a + sv.z, 0.f);
        bool m3 = my_q > qv.w;  float v3 = fmaxf(a + sv.w, 0.f);
        sum += m0 ? v0 : 0.f;   c += m0;
        sum += m1 ? v1 : 0.f;   c += m1;
        sum += m2 ? v2 : 0.f;   c += m2;
        sum += m3 ? v3 : 0.f;   c += m3;
    }

    // wave butterfly reduce
    #pragma unroll
    for (int off = 32; off >= 1; off >>= 1) {
        sum += __shfl_xor(sum, off);
        c   += __shfl_xor(c,   off);
    }
    __shared__ double   bsum[4];
    __shared__ unsigned bcnt[4];
    int w = tid >> 6;
    if ((tid & 63) == 0) { bsum[w] = (double)sum; bcnt[w] = c; }
    __syncthreads();
    if (tid == 0) {
        double   t  = bsum[0] + bsum[1] + bsum[2] + bsum[3];
        unsigned cc = bcnt[0] + bcnt[1] + bcnt[2] + bcnt[3];
        atomicAdd(total, t);
        atomicAdd(cnt, (ull)cc);
        __threadfence();
        unsigned prev = atomicAdd(done, 1u);
        if (prev == nblocks - 1) {
            // all blocks' atomics complete; read via atomic RMW to stay at the
            // device-coherent point (per-XCD L2s are not cross-coherent)
            double T = atomicAdd(total, 0.0);
            ull    C = atomicAdd(cnt, 0ull);
            if (C < 1ull) C = 1ull;
            out[0] = (float)(T / (double)C);
        }
    }
}

extern "C" void kernel_launch(void* const* d_in, const int* in_sizes, int n_in,
                              void* d_out, int out_size, void* d_ws, size_t ws_size,
                              hipStream_t stream) {
    const float* q_emb  = (const float*)d_in[0];
    const float* d_embs = (const float*)d_in[1];
    // d_in[2] = c_emb: computed-but-unused in the reference; skipped.
    const float* rates  = (const float*)d_in[3];

    int D = in_sizes[0];
    int N = in_sizes[3];

    // ws layout: [0] total(double), [8] cnt(ull), [16] done(u32), [32..] sq, qual
    double*   total = (double*)d_ws;
    ull*      cnt   = (ull*)((char*)d_ws + 8);
    unsigned* done  = (unsigned*)((char*)d_ws + 16);
    float*    sq    = (float*)((char*)d_ws + 32);
    float*    qual  = sq + N;
    float*    out   = (float*)d_out;

    int rows_per_block = 256 / 64;   // 4 waves/block, 1 row/wave
    sq_kernel<<<(N + rows_per_block - 1) / rows_per_block, 256, 0, stream>>>(
        q_emb, d_embs, rates, sq, qual, total, cnt, done, N, D);

    dim3 grid((N + 255) / 256, (N + BJ - 1) / BJ);
    pair_kernel<<<grid, 256, 0, stream>>>(sq, qual, N, total, cnt, done, out,
                                          grid.x * grid.y);
}

// Round 3
// 24.647 us; speedup vs baseline: 2.2393x; 2.2393x over previous
//
#include <hip/hip_runtime.h>

#define MARGIN 0.3f
#define ANCHOR 0.5f
#define EPS    1e-8f
#define BJ     256

typedef unsigned long long ull;

// ---------------- kernel 1: s_q and quality ----------------
// One wave (64 lanes) per row of d_embs; float4 loads; butterfly reduce.
__global__ __launch_bounds__(256) void sq_kernel(
        const float* __restrict__ q, const float* __restrict__ d,
        const float* __restrict__ rates,
        float* __restrict__ sq, float* __restrict__ qual,
        int N, int D) {
    int wave = (blockIdx.x * blockDim.x + threadIdx.x) >> 6;
    int lane = threadIdx.x & 63;
    if (wave >= N) return;
    const float* row = d + (size_t)wave * (size_t)D;

    float dot = 0.f, dn = 0.f, qn = 0.f;
    for (int it = lane * 4; it < D; it += 256) {
        float4 dv = *(const float4*)(row + it);
        float4 qv = *(const float4*)(q + it);
        dot += dv.x * qv.x + dv.y * qv.y + dv.z * qv.z + dv.w * qv.w;
        dn  += dv.x * dv.x + dv.y * dv.y + dv.z * dv.z + dv.w * dv.w;
        qn  += qv.x * qv.x + qv.y * qv.y + qv.z * qv.z + qv.w * qv.w;
    }
    #pragma unroll
    for (int off = 32; off >= 1; off >>= 1) {
        dot += __shfl_xor(dot, off);
        dn  += __shfl_xor(dn,  off);
        qn  += __shfl_xor(qn,  off);
    }
    if (lane == 0) {
        float den = fmaxf(sqrtf(dn) * sqrtf(qn), EPS);
        sq[wave]   = dot / den;
        qual[wave] = fabsf(rates[wave] - ANCHOR);
    }
}

// ---------------- kernel 2: N^2 pair partials (NO contended atomics) ----------------
// grid = (N/256, N/BJ). Thread owns i (registers); j-tile staged in LDS as
// float2 {sq, qual}; uniform ds_read_b64 -> broadcast, conflict-free.
// Block partial goes to psum[bid]/pcnt[bid] via plain stores.
__global__ __launch_bounds__(256) void pair_kernel(
        const float* __restrict__ sq, const float* __restrict__ qual,
        int N, double* __restrict__ psum, unsigned* __restrict__ pcnt) {
    __shared__ float2 tile[BJ];

    int tid = threadIdx.x;
    int i   = blockIdx.x * blockDim.x + tid;
    int j0  = blockIdx.y * BJ;

    if (tid < BJ) {
        int j = j0 + tid;
        tile[tid] = make_float2(j < N ? sq[j] : 0.f,
                                j < N ? qual[j] : 1e30f);  // huge qual -> never counted
    }
    __syncthreads();

    float my_sq = (i < N) ? sq[i]   : 0.f;
    float my_q  = (i < N) ? qual[i] : -1.f;   // quality >= 0 -> masks everything off
    float a     = MARGIN - my_sq;

    float sum = 0.f;
    unsigned c = 0;
    #pragma unroll 8
    for (int j = 0; j < BJ; ++j) {
        float2 t = tile[j];
        bool  m = my_q > t.y;
        float v = fmaxf(a + t.x, 0.f);
        sum += m ? v : 0.f;
        c   += m ? 1u : 0u;
    }

    // wave butterfly reduce
    #pragma unroll
    for (int off = 32; off >= 1; off >>= 1) {
        sum += __shfl_xor(sum, off);
        c   += __shfl_xor(c,   off);
    }
    __shared__ double   bsum[4];
    __shared__ unsigned bcnt[4];
    int w = tid >> 6;
    if ((tid & 63) == 0) { bsum[w] = (double)sum; bcnt[w] = c; }
    __syncthreads();
    if (tid == 0) {
        int bid = blockIdx.y * gridDim.x + blockIdx.x;
        psum[bid] = bsum[0] + bsum[1] + bsum[2] + bsum[3];
        pcnt[bid] = bcnt[0] + bcnt[1] + bcnt[2] + bcnt[3];
    }
}

// ---------------- kernel 3: reduce partials, finalize ----------------
__global__ __launch_bounds__(256) void reduce_kernel(
        const double* __restrict__ psum, const unsigned* __restrict__ pcnt,
        int nb, float* __restrict__ out) {
    int tid = threadIdx.x;
    double s = 0.0;
    ull    c = 0ull;
    for (int k = tid; k < nb; k += 256) {
        s += psum[k];
        c += (ull)pcnt[k];
    }
    #pragma unroll
    for (int off = 32; off >= 1; off >>= 1) {
        s += __shfl_xor(s, off);
        c += __shfl_xor(c, off);
    }
    __shared__ double bsum[4];
    __shared__ ull    bcnt[4];
    int w = tid >> 6;
    if ((tid & 63) == 0) { bsum[w] = s; bcnt[w] = c; }
    __syncthreads();
    if (tid == 0) {
        double T = bsum[0] + bsum[1] + bsum[2] + bsum[3];
        ull    C = bcnt[0] + bcnt[1] + bcnt[2] + bcnt[3];
        if (C < 1ull) C = 1ull;
        out[0] = (float)(T / (double)C);
    }
}

extern "C" void kernel_launch(void* const* d_in, const int* in_sizes, int n_in,
                              void* d_out, int out_size, void* d_ws, size_t ws_size,
                              hipStream_t stream) {
    const float* q_emb  = (const float*)d_in[0];
    const float* d_embs = (const float*)d_in[1];
    // d_in[2] = c_emb: computed-but-unused in the reference; skipped.
    const float* rates  = (const float*)d_in[3];

    int D = in_sizes[0];
    int N = in_sizes[3];

    dim3 grid((N + 255) / 256, (N + BJ - 1) / BJ);
    int  nb = grid.x * grid.y;

    // ws layout: psum[nb] (8B each), pcnt[nb] (4B), then sq[N], qual[N]
    double*   psum = (double*)d_ws;
    unsigned* pcnt = (unsigned*)(psum + nb);
    float*    sq   = (float*)(pcnt + nb + (nb & 1));   // keep 8B alignment
    float*    qual = sq + N;
    float*    out  = (float*)d_out;

    int rows_per_block = 256 / 64;   // 4 waves/block, 1 row/wave
    sq_kernel<<<(N + rows_per_block - 1) / rows_per_block, 256, 0, stream>>>(
        q_emb, d_embs, rates, sq, qual, N, D);

    pair_kernel<<<grid, 256, 0, stream>>>(sq, qual, N, psum, pcnt);

    reduce_kernel<<<1, 256, 0, stream>>>(psum, pcnt, nb, out);
}